// Round 6
// baseline (704.552 us; speedup 1.0000x reference)
//
#include <hip/hip_runtime.h>
#include <math.h>

#define T      512
#define NBATCH 512
#define IN_DIM 64
#define H      100
#define KP     208          // padded contraction rows per layer input vector
#define PBYTES 832          // KP*4: byte stride between parity buffers

// tanh(a) = 1 - 2/(exp(2a)+1)  -- overflow-safe at both ends.
__device__ __forceinline__ float fast_tanh(float a) {
    float e = __expf(2.0f * a);
    return 1.0f - 2.0f / (e + 1.0f);
}

#define DPPMOV(x, ctrl) __int_as_float(__builtin_amdgcn_update_dpp( \
        0, __float_as_int(x), (ctrl), 0xF, 0xF, true))

// weight element, 0 if col out of range or row in pad region.
// concat rows: [0,kA) -> WA, [kA,kA+100) -> WB, else 0.
__device__ __forceinline__ float wvalc(const float* __restrict__ WA,
                                       const float* __restrict__ WB,
                                       int kA, int R, int col) {
    if (col >= H) return 0.f;
    if (R < kA) return WA[R * H + col];
    int rr = R - kA;
    return (rr < H) ? WB[rr * H + col] : 0.f;
}

__device__ __forceinline__ float4 wload4c(const float* __restrict__ WA,
                                          const float* __restrict__ WB,
                                          int kA, int R0, int col) {
    return make_float4(wvalc(WA, WB, kA, R0 + 0, col),
                       wvalc(WA, WB, kA, R0 + 1, col),
                       wvalc(WA, WB, kA, R0 + 2, col),
                       wvalc(WA, WB, kA, R0 + 3, col));
}

// ---------------------------------------------------------------------------
// 512-thread block, one batch element, __launch_bounds__(512,4): 16 waves/CU
// (the best-measured TLP regime, R1=477us) with a STRICT <=128-reg live set
// (R4's identical geometry spilled at ~136 live: WRITE_SIZE 12MB, 846us).
// Unit = 16 lanes; 8 cols/unit. Units 0-12 = L1, 13-25 = L2 (one timestep
// behind); wave 7 = x-prefetch (1-reg pipeline); units 26-27 + rest idle.
// Per thread: 13 K-floats x 8 cols = 104 weight floats, 104 fmaf, and only
// 3 ds_read_b128 (+1 b32 L2-only) per DOT vs R1's 7 ds-ops -- the LDS pipe
// was ~half of R1's 2236-cycle body.
// Register discipline vs R4: single reused float4 activation buffer (4 regs
// not 13; 4 waves/SIMD hides the read serialization), XOR-indexed select-
// free merge (no q-flag regs, no cndmasks), L1 skips tail read+FMAs,
// 1-reg x pipeline. Peak live ~125.
// Merge (validated on HW in R2/R5): acc k at lane l holds col j+(k^c3),
// c3=(l&3)|((l>>1)&4). xor1 (quad_perm 0xB1) folds k-bit0, xor2 (0x4E)
// k-bit1, xor8 (row_ror:8, 0x128) k-bit2, final ^4 (half_mirror o quad3 =
// 0x141 then 0x1B) sums the pure-K lane bit2. Lane l ends with col j+c3,
// duplicated in lanes l and l^4 -> the pair carries L1's two stores.
// ---------------------------------------------------------------------------

#define K8(X) X(0) X(1) X(2) X(3) X(4) X(5) X(6) X(7)

#define WDECL(k) float4 w0_##k={0,0,0,0}, w1_##k={0,0,0,0}, w2_##k={0,0,0,0}; \
                 float wt##k = 0.f;
#define WLOAD(k) { const int ck_ = j + ((k) ^ c3l);            \
    w0_##k = wload4c(WA, WB, kA,       4*l, ck_);              \
    w1_##k = wload4c(WA, WB, kA,  64 + 4*l, ck_);              \
    w2_##k = wload4c(WA, WB, kA, 128 + 4*l, ck_);              \
    wt##k  = wvalc (WA, WB, kA, 192 + l,   ck_); }

#define ADECL(k) float a##k = 0.f;
#define FR0(k) { a##k = fmaf(va.x, w0_##k.x, a##k); a##k = fmaf(va.y, w0_##k.y, a##k); \
                 a##k = fmaf(va.z, w0_##k.z, a##k); a##k = fmaf(va.w, w0_##k.w, a##k); }
#define FR1(k) { a##k = fmaf(va.x, w1_##k.x, a##k); a##k = fmaf(va.y, w1_##k.y, a##k); \
                 a##k = fmaf(va.z, w1_##k.z, a##k); a##k = fmaf(va.w, w1_##k.w, a##k); }
#define FR2(k) { a##k = fmaf(va.x, w2_##k.x, a##k); a##k = fmaf(va.y, w2_##k.y, a##k); \
                 a##k = fmaf(va.z, w2_##k.z, a##k); a##k = fmaf(va.w, w2_##k.w, a##k); }
#define FT(k)  { a##k = fmaf(vt_, wt##k, a##k); }

#define DOT(P, hv) {                                              \
    K8(ADECL)                                                     \
    float4 va = *(const float4*)(rb + (P));                       \
    K8(FR0)                                                       \
    va = *(const float4*)(rb + (P) + 256);                        \
    K8(FR1)                                                       \
    va = *(const float4*)(rb + (P) + 512);                        \
    K8(FR2)                                                       \
    if (!isL1) {                                                  \
        const float vt_ = *(const float*)(tb + (P));              \
        K8(FT)                                                    \
    }                                                             \
    float u0_ = a0 + DPPMOV(a1, 0xB1);                            \
    float u1_ = a2 + DPPMOV(a3, 0xB1);                            \
    float u2_ = a4 + DPPMOV(a5, 0xB1);                            \
    float u3_ = a6 + DPPMOV(a7, 0xB1);                            \
    float r0_ = u0_ + DPPMOV(u1_, 0x4E);                          \
    float r1_ = u2_ + DPPMOV(u3_, 0x4E);                          \
    float z_  = r0_ + DPPMOV(r1_, 0x128);                         \
    z_ += DPPMOV(DPPMOV(z_, 0x141), 0x1B);                        \
    hv = fast_tanh(z_ + bj); }

__global__ __launch_bounds__(512, 4)
void drnn_kernel(const float* __restrict__ x,
                 const float* __restrict__ W1x, const float* __restrict__ W1h,
                 const float* __restrict__ b1,
                 const float* __restrict__ W2x, const float* __restrict__ W2h,
                 const float* __restrict__ b2,
                 const float* __restrict__ Wo,  const float* __restrict__ bo,
                 float* __restrict__ out)
{
    // in1: [x_t (64) | h1 (100) | pad->208]; in2: [h1 (100) | h2 (100) | pad->208]
    __shared__ __align__(16) float in1[2][KP];
    __shared__ __align__(16) float in2[2][KP];

    const int tid    = threadIdx.x;
    const int b      = blockIdx.x;
    const int l      = tid & 15;                 // K-slice within 16-lane unit
    const int unit   = tid >> 4;                 // 0..31
    const int lane64 = tid & 63;
    const bool comp  = (unit < 26);              // 13 L1 + 13 L2 units
    const bool isL1  = (unit < 13);
    const bool isXW  = (tid >= 448);             // wave 7: x-prefetch

    const float* __restrict__ xrow = x + (size_t)b * T * IN_DIM;

    // ---- zero-init LDS (pads must stay 0; h(-1)=0; h2(-1) slot stays 0) ----
    for (int k = tid; k < 2 * KP; k += 512) {
        (&in1[0][0])[k] = 0.f;
        (&in2[0][0])[k] = 0.f;
    }
    if (tid < IN_DIM) in1[0][tid] = xrow[tid];   // x(0)

    const float* __restrict__ WA = isL1 ? W1x : W2x;
    const float* __restrict__ WB = isL1 ? W1h : W2h;
    const int kA  = isL1 ? IN_DIM : H;           // rows [0,kA)->WA, [kA,kA+100)->WB
    const int ul  = isL1 ? unit : unit - 13;
    const int j   = 8 * ((ul >= 0 && ul < 13) ? ul : 0);   // col base <= 96
    const int c3l = (l & 3) | ((l >> 1) & 4);    // col-in-unit via lane bits {0,1,3}
    const int n   = j + c3l;                     // col this lane finalizes (0..103)
    const int nc  = (n < H) ? n : H - 1;
    const float bj = comp ? (isL1 ? b1 : b2)[nc] : 0.f;

    // ---- 104 weight floats: 24 float4 (rounds 0-2) + 8 tail (L2 nonzero) ----
    K8(WDECL)
    if (comp) { K8(WLOAD) }

    // ---- per-lane LDS pointers; odd parity via +PBYTES immediate ----
    const char* rb = (const char*)(isL1 ? &in1[0][0] : &in2[0][0]) + 16 * l;
    const char* tb = (const char*)&in2[0][0] + 768 + 4 * l;   // tail row 192+l

    // parity-0 store slot; dup pair (l, l^4) splits L1's two destinations
    char* stp; bool dow;
    if (isL1) { stp = (char*)((l & 4) ? &in2[0][n] : &in1[0][64 + n]);
                dow = comp && (n < H); }
    else      { stp = (char*)&in2[0][100 + n];
                dow = comp && (n < H) && !(l & 4); }

    // ---- 1-reg x pipeline (wave 7): each load has a full body to land ----
    char* xw = (char*)&in1[0][lane64];
    float xr = 0.f;
    if (isXW) xr = xrow[IN_DIM + lane64];        // x(1)

    __syncthreads();

    // Body i: L1 computes h1(i); L2 computes h2(i-1).
    #pragma unroll 1
    for (int i = 0; i < T; i += 2) {
        // ---- even body: read parity 0, write parity 1 ----
        if (comp) {
            float hv; DOT(0, hv)
            if (dow && (isL1 || i > 0)) *(float*)(stp + PBYTES) = hv; // skip bogus h2(-1)
        } else if (isXW) {
            *(float*)(xw + PBYTES) = xr;         // x(i+1) -> parity 1
            if (i + 2 < T) xr = xrow[(size_t)(i + 2) * IN_DIM + lane64];
        }
        __syncthreads();
        // ---- odd body: read parity 1, write parity 0 ----
        if (comp) {
            float hv; DOT(PBYTES, hv)
            if (dow) *(float*)stp = hv;
        } else if (isXW) {
            *(float*)xw = xr;                    // x(i+2) -> parity 0
            if (i + 3 < T) xr = xrow[(size_t)(i + 3) * IN_DIM + lane64];
        }
        __syncthreads();
    }

    // ---- tail body (parity 0): only L2, computes h2(T-1) ----
    if (comp && !isL1) {
        float hv; DOT(0, hv)
        if (dow) *(float*)(stp + PBYTES) = hv;   // -> in2[1][100..]
    }
    __syncthreads();

    // ---- epilogue: h1(T-1) in in1[0][64..], h2(T-1) in in2[1][100..] ----
    if (tid < H)
        out[NBATCH + (size_t)b * H + tid] = in1[0][64 + tid];
    if (tid < H)
        out[NBATCH + (size_t)NBATCH * H + (size_t)b * H + tid] = in2[1][100 + tid];

    // out[b] = h2_T . Wo + bo  (wave-0 shuffle reduction)
    if (tid < 64) {
        float v = in2[1][100 + tid] * Wo[tid];
        if (tid + 64 < H) v += in2[1][100 + 64 + tid] * Wo[tid + 64];
        #pragma unroll
        for (int off = 32; off >= 1; off >>= 1) v += __shfl_down(v, off);
        if (tid == 0) out[b] = v + bo[0];
    }
}

extern "C" void kernel_launch(void* const* d_in, const int* in_sizes, int n_in,
                              void* d_out, int out_size, void* d_ws, size_t ws_size,
                              hipStream_t stream) {
    const float* x   = (const float*)d_in[0];
    const float* W1x = (const float*)d_in[1];
    const float* W1h = (const float*)d_in[2];
    const float* b1  = (const float*)d_in[3];
    const float* W2x = (const float*)d_in[4];
    const float* W2h = (const float*)d_in[5];
    const float* b2  = (const float*)d_in[6];
    const float* Wo  = (const float*)d_in[7];
    const float* bo  = (const float*)d_in[8];
    float* out = (float*)d_out;

    drnn_kernel<<<NBATCH, 512, 0, stream>>>(x, W1x, W1h, b1, W2x, W2h, b2,
                                            Wo, bo, out);
}

// Round 7
// 499.121 us; speedup vs baseline: 1.4116x; 1.4116x over previous
//
#include <hip/hip_runtime.h>
#include <math.h>

#define T      512
#define NBATCH 512
#define IN_DIM 64
#define H      100
#define KP     208          // padded contraction rows per layer input vector
#define PBYTES 832          // KP*4: byte stride between parity buffers

// tanh(a) = 1 - 2/(exp(2a)+1)  -- overflow-safe at both ends.
__device__ __forceinline__ float fast_tanh(float a) {
    float e = __expf(2.0f * a);
    return 1.0f - 2.0f / (e + 1.0f);
}

// Full-butterfly DPP add: every lane gets the pairwise sum.
#define DPP_ADD(v, ctrl) ((v) + __int_as_float(__builtin_amdgcn_update_dpp( \
        0, __float_as_int(v), (ctrl), 0xF, 0xF, true)))
#define RED8(a) { (a) = DPP_ADD((a), 0xB1);   /* xor 1 (quad_perm) */ \
                  (a) = DPP_ADD((a), 0x4E);   /* xor 2 (quad_perm) */ \
                  (a) = DPP_ADD((a), 0x128);  /* xor 8 (row_ror:8) */ }

// weight element for concatenated row R: rows [0,kA) -> WA, [kA,kA+100) -> WB, else 0
__device__ __forceinline__ float wval(const float* __restrict__ WA,
                                      const float* __restrict__ WB,
                                      int kA, int R, int col) {
    if (R < kA) return WA[R * H + col];
    int rr = R - kA;
    return (rr < H) ? WB[rr * H + col] : 0.f;
}

__device__ __forceinline__ float4 wload4(const float* __restrict__ WA,
                                         const float* __restrict__ WB,
                                         int kA, int R0, int col) {
    return make_float4(wval(WA, WB, kA, R0 + 0, col),
                       wval(WA, WB, kA, R0 + 1, col),
                       wval(WA, WB, kA, R0 + 2, col),
                       wval(WA, WB, kA, R0 + 3, col));
}

// ---------------------------------------------------------------------------
// TWO batch elements per 1024-thread block; each 512-thread half (t = tid&511,
// e = tid>>9) is byte-identical to the proven 477us champion: 8-way K-split
// (s = lane bits {0,1,3}), 4 cols/group (g = lane bits {2,4,5}), 25 L1 + 25 L2
// groups over waves 0-6, wave 7 = x-prefetch. Per thread: 104 weight floats
// (24 float4 + 4 float2 tails), 104 fmaf, 6 ds_read_b128 + 1 b64 per DOT,
// all-DPP RED8 reduction (zero LDS-pipe traffic), live set ~118 < 128 (the
// 8-acc variants R4/R6 at ~130 live spilled and died: WRITE_SIZE 8-12 MB).
// Mechanism of this round: the shared barriers amortize per-timestep barrier/
// phase-serialization overhead over 2 elements, and each barrier interval now
// has 2x independent work to overlap the LDS pipe with the SIMDs. Grid = 256
// = exactly 1 block/CU (16 waves, 4/SIMD -- same TLP, no dispatch jitter).
// ---------------------------------------------------------------------------

#define RNDS(X) X(0) X(1) X(2) X(3) X(4) X(5)

#define WDECL(R) float4 w##R##_0 = {0,0,0,0}, w##R##_1 = {0,0,0,0}, \
                        w##R##_2 = {0,0,0,0}, w##R##_3 = {0,0,0,0};

#define WLOAD(R) { const int r0_ = 32 * (R) + 4 * s;   \
    w##R##_0 = wload4(WA, WB, kA, r0_, j + 0);         \
    w##R##_1 = wload4(WA, WB, kA, r0_, j + 1);         \
    w##R##_2 = wload4(WA, WB, kA, r0_, j + 2);         \
    w##R##_3 = wload4(WA, WB, kA, r0_, j + 3); }

#define FSTEP(R, P) { const float4 v_ = *(const float4*)(rb + (P) + 128 * (R)); \
    a0 = fmaf(v_.x, w##R##_0.x, a0); a1 = fmaf(v_.x, w##R##_1.x, a1);           \
    a2 = fmaf(v_.x, w##R##_2.x, a2); a3 = fmaf(v_.x, w##R##_3.x, a3);           \
    a0 = fmaf(v_.y, w##R##_0.y, a0); a1 = fmaf(v_.y, w##R##_1.y, a1);           \
    a2 = fmaf(v_.y, w##R##_2.y, a2); a3 = fmaf(v_.y, w##R##_3.y, a3);           \
    a0 = fmaf(v_.z, w##R##_0.z, a0); a1 = fmaf(v_.z, w##R##_1.z, a1);           \
    a2 = fmaf(v_.z, w##R##_2.z, a2); a3 = fmaf(v_.z, w##R##_3.z, a3);           \
    a0 = fmaf(v_.w, w##R##_0.w, a0); a1 = fmaf(v_.w, w##R##_1.w, a1);           \
    a2 = fmaf(v_.w, w##R##_2.w, a2); a3 = fmaf(v_.w, w##R##_3.w, a3); }

#define DOT(P, hv) {                                                      \
    float a0 = 0.f, a1 = 0.f, a2 = 0.f, a3 = 0.f;                         \
    FSTEP(0, P) FSTEP(1, P) FSTEP(2, P)                                   \
    FSTEP(3, P) FSTEP(4, P) FSTEP(5, P)                                   \
    { const float2 v_ = *(const float2*)(tb + (P));                       \
      a0 = fmaf(v_.x, wt0.x, a0); a1 = fmaf(v_.x, wt1.x, a1);             \
      a2 = fmaf(v_.x, wt2.x, a2); a3 = fmaf(v_.x, wt3.x, a3);             \
      a0 = fmaf(v_.y, wt0.y, a0); a1 = fmaf(v_.y, wt1.y, a1);             \
      a2 = fmaf(v_.y, wt2.y, a2); a3 = fmaf(v_.y, wt3.y, a3); }           \
    RED8(a0) RED8(a1) RED8(a2) RED8(a3)                                   \
    const float t01_ = (s & 1) ? a1 : a0;                                 \
    const float t23_ = (s & 1) ? a3 : a2;                                 \
    hv = fast_tanh(((s & 2) ? t23_ : t01_) + bj); }

__global__ __launch_bounds__(1024, 4)
void drnn_kernel(const float* __restrict__ x,
                 const float* __restrict__ W1x, const float* __restrict__ W1h,
                 const float* __restrict__ b1,
                 const float* __restrict__ W2x, const float* __restrict__ W2h,
                 const float* __restrict__ b2,
                 const float* __restrict__ Wo,  const float* __restrict__ bo,
                 float* __restrict__ out)
{
    // per elem: in1 = [x_t(64) | h1(100) | pad->208]; in2 = [h1(100) | h2(100) | pad]
    __shared__ __align__(16) float in1[2][2][KP];   // [elem][parity][KP]
    __shared__ __align__(16) float in2[2][2][KP];

    const int tid  = threadIdx.x;
    const int e    = tid >> 9;                   // which batch element (0/1)
    const int t    = tid & 511;                  // thread id within the half
    const int b    = 2 * blockIdx.x + e;
    const int lane = t & 63;
    const int wv   = t >> 6;
    const int s    = (lane & 3) | ((lane >> 1) & 4);        // K-slice: lane bits {0,1,3}
    const int gw   = ((lane >> 2) & 1) | ((lane >> 3) & 6); // group-in-wave: bits {2,4,5}
    const int gg   = wv * 8 + gw;                           // global group 0..63
    const bool active = (gg < 50);               // 25 L1 + 25 L2 groups
    const bool isL1   = (gg < 25);
    const bool isXL   = (wv == 7);               // x-prefetch wave

    const float* __restrict__ xrow = x + (size_t)b * T * IN_DIM;

    // ---- zero-init this elem's LDS (pads stay 0; h(-1)=0; h2(-1) stays 0) ----
    for (int k = t; k < 2 * KP; k += 512) {
        (&in1[e][0][0])[k] = 0.f;
        (&in2[e][0][0])[k] = 0.f;
    }
    if (t < IN_DIM) in1[e][0][t] = xrow[t];      // x(0)

    const float* __restrict__ WA = isL1 ? W1x : W2x;
    const float* __restrict__ WB = isL1 ? W1h : W2h;
    const int kA = isL1 ? IN_DIM : H;            // rows [0,kA)->WA, [kA,kA+100)->WB
    const int gl = isL1 ? gg : gg - 25;
    const int nl = (gl >= 0 && gl < 25) ? gl : 0;
    const int j  = 4 * nl;                       // col base (exact: 4*24+3 = 99 max)
    const int n  = j + (s & 3);                  // col this lane finalizes
    const float bj = active ? (isL1 ? b1 : b2)[n] : 0.f;

    // ---- 104 named weight floats: 24 float4 + 4 float2 (tail rows 192..207) ----
    RNDS(WDECL)
    float2 wt0 = {0,0}, wt1 = {0,0}, wt2 = {0,0}, wt3 = {0,0};
    if (active) {
        RNDS(WLOAD)
        const int rt = 192 + 2 * s;
        wt0 = make_float2(wval(WA,WB,kA,rt,j+0), wval(WA,WB,kA,rt+1,j+0));
        wt1 = make_float2(wval(WA,WB,kA,rt,j+1), wval(WA,WB,kA,rt+1,j+1));
        wt2 = make_float2(wval(WA,WB,kA,rt,j+2), wval(WA,WB,kA,rt+1,j+2));
        wt3 = make_float2(wval(WA,WB,kA,rt,j+3), wval(WA,WB,kA,rt+1,j+3));
    }

    // ---- per-lane LDS pointers; odd parity reached via +PBYTES immediate ----
    const char* lb = (const char*)(isL1 ? &in1[e][0][0] : &in2[e][0][0]);
    const char* rb = lb + 16 * s;                // round R at byte offset P + 128*R
    const char* tb = lb + 768 + 8 * s;           // float2 tail rows 192+2s

    // parity-0 store slot; dup pair (s, s+4) carries L1's two destinations
    char* st;
    if (isL1) st = (char*)((s < 4) ? &in1[e][0][64 + n] : &in2[e][0][n]);
    else      st = (char*)&in2[e][0][100 + n];
    const bool dost = active && (isL1 || s < 4);

    // ---- x register pipeline (wave 7 of this half), two steps ahead ----
    char* xw = (char*)&in1[e][0][lane];
    float xr0 = 0.f, xr1 = 0.f;
    if (isXL) {
        xr0 = xrow[1 * IN_DIM + lane];           // x(1)
        xr1 = xrow[2 * IN_DIM + lane];           // x(2)
    }

    __syncthreads();

    // Body i: L1 computes h1(i); L2 computes h2(i-1). Wave 7 stages x(i+1).
    #pragma unroll 1
    for (int i = 0; i < T; i += 2) {
        // ---- even body: read parity 0, write parity 1 ----
        if (active) {
            float hv; DOT(0, hv)
            if (dost && (isL1 || i > 0)) *(float*)(st + PBYTES) = hv; // skip bogus h2(-1)
        } else if (isXL) {
            *(float*)(xw + PBYTES) = xr0;        // x(i+1)
            xr0 = xr1;
            if (i + 3 < T) xr1 = xrow[(size_t)(i + 3) * IN_DIM + lane];
        }
        __syncthreads();
        // ---- odd body: read parity 1, write parity 0 ----
        if (active) {
            float hv; DOT(PBYTES, hv)
            if (dost) *(float*)st = hv;
        } else if (isXL) {
            *(float*)xw = xr0;                   // x(i+2)
            xr0 = xr1;
            if (i + 4 < T) xr1 = xrow[(size_t)(i + 4) * IN_DIM + lane];
        }
        __syncthreads();
    }

    // ---- tail body (parity 0): only L2, computes h2(T-1) ----
    if (active && !isL1) {
        float hv; DOT(0, hv)                     // in2[e][0]: h1(T-1) + h2(T-2)
        if (dost) *(float*)(st + PBYTES) = hv;   // -> in2[e][1][100..]
    }
    __syncthreads();

    // ---- epilogue: h1(T-1) in in1[e][0][64..], h2(T-1) in in2[e][1][100..] ----
    if (t < H)
        out[NBATCH + (size_t)b * H + t] = in1[e][0][64 + t];
    if (t < H)
        out[NBATCH + (size_t)NBATCH * H + (size_t)b * H + t] = in2[e][1][100 + t];

    // out[b] = h2_T . Wo + bo  (one wave per half does the shuffle reduction)
    if (t < 64) {
        float v = in2[e][1][100 + t] * Wo[t];
        if (t + 64 < H) v += in2[e][1][100 + 64 + t] * Wo[t + 64];
        #pragma unroll
        for (int off = 32; off >= 1; off >>= 1) v += __shfl_down(v, off);
        if (t == 0) out[b] = v + bo[0];
    }
}

extern "C" void kernel_launch(void* const* d_in, const int* in_sizes, int n_in,
                              void* d_out, int out_size, void* d_ws, size_t ws_size,
                              hipStream_t stream) {
    const float* x   = (const float*)d_in[0];
    const float* W1x = (const float*)d_in[1];
    const float* W1h = (const float*)d_in[2];
    const float* b1  = (const float*)d_in[3];
    const float* W2x = (const float*)d_in[4];
    const float* W2h = (const float*)d_in[5];
    const float* b2  = (const float*)d_in[6];
    const float* Wo  = (const float*)d_in[7];
    const float* bo  = (const float*)d_in[8];
    float* out = (float*)d_out;

    drnn_kernel<<<NBATCH / 2, 1024, 0, stream>>>(x, W1x, W1h, b1, W2x, W2h, b2,
                                                 Wo, bo, out);
}